// Round 1
// baseline (1285.041 us; speedup 1.0000x reference)
//
#include <hip/hip_runtime.h>
#include <hip/hip_bf16.h>

typedef __bf16 v8bf __attribute__((ext_vector_type(8)));
typedef float  f32x4 __attribute__((ext_vector_type(4)));

#define KVOL 27

__device__ __forceinline__ unsigned short f2bf(float f) {
    unsigned int u = __float_as_uint(f);
    u = u + 0x7FFFu + ((u >> 16) & 1u);   // round-to-nearest-even
    return (unsigned short)(u >> 16);
}

// ---------------------------------------------------------------------------
// Prep: W [27][64in][64out] fp32 -> bf16 B-fragments for mfma_f32_16x16x32_bf16.
// Fragment layout: for tap k, col-tile t (16 outc), K-step s (32 inc):
//   lane l, elem i  holds  W[k][ s*32 + (l>>4)*8 + i ][ t*16 + (l&15) ]
// stored at linear ushort index (((k*4+t)*2+s)*64 + l)*8 + i.
// Also zeroes the 128-float stats accumulator.
// ---------------------------------------------------------------------------
__global__ __launch_bounds__(256) void prep_kernel(const float* __restrict__ W,
                                                   unsigned short* __restrict__ wfrag,
                                                   float* __restrict__ stats) {
    if (blockIdx.x == 0 && threadIdx.x < 128) stats[threadIdx.x] = 0.0f;
    int d = blockIdx.x * 256 + threadIdx.x;
    if (d < KVOL * 64 * 64) {
        int i    = d & 7;
        int lane = (d >> 3) & 63;
        int s    = (d >> 9) & 1;
        int t    = (d >> 10) & 3;
        int k    = d >> 12;
        int kin  = s * 32 + (lane >> 4) * 8 + i;
        int c    = t * 16 + (lane & 15);
        wfrag[d] = f2bf(W[k * 4096 + kin * 64 + c]);
    }
}

// ---------------------------------------------------------------------------
// Conv + scatter: block = 64 points, 4 waves. Wave w owns point-rows
// [16w, 16w+16). Per tap k: C[16x64] = A[16x64] * W_k[64x64] via 8 MFMAs,
// then atomic-scatter rows to out[out_idx[p][k]].
// ---------------------------------------------------------------------------
__global__ __launch_bounds__(256) void conv_scatter(const float* __restrict__ feats,
                                                    const unsigned short* __restrict__ wfrag,
                                                    const int* __restrict__ oidx,
                                                    float* __restrict__ out,
                                                    int Npts) {
    __shared__ unsigned short As[64 * 64];   // bf16 A tile [point][inc]
    __shared__ int Is[64 * KVOL];            // out_idx tile

    const int tid  = threadIdx.x;
    const int base = blockIdx.x * 64;

    // Stage A (fp32 -> bf16), zero-fill invalid rows.
    #pragma unroll
    for (int e = 0; e < 4; ++e) {
        int lin = e * 1024 + tid * 4;
        int row = lin >> 6, col = lin & 63;
        float4 v = make_float4(0.f, 0.f, 0.f, 0.f);
        if (base + row < Npts)
            v = *reinterpret_cast<const float4*>(feats + (size_t)(base + row) * 64 + col);
        As[lin + 0] = f2bf(v.x);
        As[lin + 1] = f2bf(v.y);
        As[lin + 2] = f2bf(v.z);
        As[lin + 3] = f2bf(v.w);
    }
    // Stage out_idx (contiguous copy).
    for (int lin = tid; lin < 64 * KVOL; lin += 256) {
        int g = base * KVOL + lin;
        Is[lin] = (g < Npts * KVOL) ? oidx[g] : 0;
    }
    __syncthreads();

    const int w  = tid >> 6;
    const int l  = tid & 63;
    const int cl = l & 15;     // A-row / C-col within tile
    const int hi = l >> 4;

    const v8bf a0 = *reinterpret_cast<const v8bf*>(&As[(16 * w + cl) * 64 + hi * 8]);
    const v8bf a1 = *reinterpret_cast<const v8bf*>(&As[(16 * w + cl) * 64 + 32 + hi * 8]);
    const v8bf* wf = reinterpret_cast<const v8bf*>(wfrag);

    for (int k = 0; k < KVOL; ++k) {
        f32x4 acc[4];
        #pragma unroll
        for (int t = 0; t < 4; ++t) acc[t] = (f32x4){0.f, 0.f, 0.f, 0.f};

        #pragma unroll
        for (int t = 0; t < 4; ++t) {
            v8bf b0 = wf[((k * 4 + t) * 2 + 0) * 64 + l];
            v8bf b1 = wf[((k * 4 + t) * 2 + 1) * 64 + l];
            acc[t] = __builtin_amdgcn_mfma_f32_16x16x32_bf16(a0, b0, acc[t], 0, 0, 0);
            acc[t] = __builtin_amdgcn_mfma_f32_16x16x32_bf16(a1, b1, acc[t], 0, 0, 0);
        }

        #pragma unroll
        for (int r = 0; r < 4; ++r) {
            int lrow = 16 * w + hi * 4 + r;       // C row within block tile
            if (base + lrow < Npts) {
                int o = Is[lrow * KVOL + k];
                float* dst = out + (size_t)o * 64 + cl;
                #pragma unroll
                for (int t = 0; t < 4; ++t)
                    unsafeAtomicAdd(dst + t * 16, acc[t][r]);
            }
        }
    }
}

// ---------------------------------------------------------------------------
// Per-channel sum / sumsq over out [Nout][64].
// ---------------------------------------------------------------------------
__global__ __launch_bounds__(256) void bn_stats(const float* __restrict__ out,
                                                float* __restrict__ stats,
                                                int Nout) {
    const int tid = threadIdx.x;
    const int cg  = tid & 15;    // channel group (4 ch)
    const int rs  = tid >> 4;    // row slot
    f32x4 s = {0.f, 0.f, 0.f, 0.f}, q = {0.f, 0.f, 0.f, 0.f};
    for (long r = (long)blockIdx.x * 16 + rs; r < Nout; r += (long)gridDim.x * 16) {
        f32x4 v = *reinterpret_cast<const f32x4*>(out + (size_t)r * 64 + cg * 4);
        s += v;
        q += v * v;
    }
    __shared__ f32x4 sd[256];
    __shared__ f32x4 qd[256];
    sd[tid] = s; qd[tid] = q;
    __syncthreads();
    #pragma unroll
    for (int st = 8; st >= 1; st >>= 1) {
        if (rs < st) { sd[tid] += sd[tid + 16 * st]; qd[tid] += qd[tid + 16 * st]; }
        __syncthreads();
    }
    if (rs == 0) {
        #pragma unroll
        for (int c = 0; c < 4; ++c) {
            unsafeAtomicAdd(&stats[cg * 4 + c],      sd[tid][c]);
            unsafeAtomicAdd(&stats[64 + cg * 4 + c], qd[tid][c]);
        }
    }
}

// ---------------------------------------------------------------------------
// y = gamma*(x-mean)*rsqrt(var+eps)+beta, then LeakyReLU(0.01). In place.
// ---------------------------------------------------------------------------
__global__ __launch_bounds__(256) void bn_apply(float* __restrict__ out,
                                                const float* __restrict__ stats,
                                                const float* __restrict__ gamma,
                                                const float* __restrict__ beta,
                                                int Nout) {
    const int tid = threadIdx.x;
    const int cg  = tid & 15;
    const int rs  = tid >> 4;
    const float inv = 1.0f / (float)Nout;
    f32x4 scale, shift;
    #pragma unroll
    for (int c = 0; c < 4; ++c) {
        float m   = stats[cg * 4 + c] * inv;
        float var = stats[64 + cg * 4 + c] * inv - m * m;
        float sc  = gamma[cg * 4 + c] * rsqrtf(var + 1e-5f);
        scale[c]  = sc;
        shift[c]  = beta[cg * 4 + c] - sc * m;
    }
    for (long r = (long)blockIdx.x * 16 + rs; r < Nout; r += (long)gridDim.x * 16) {
        f32x4* p = reinterpret_cast<f32x4*>(out + (size_t)r * 64 + cg * 4);
        f32x4 v = *p;
        v = v * scale + shift;
        #pragma unroll
        for (int c = 0; c < 4; ++c) v[c] = v[c] > 0.f ? v[c] : 0.01f * v[c];
        *p = v;
    }
}

extern "C" void kernel_launch(void* const* d_in, const int* in_sizes, int n_in,
                              void* d_out, int out_size, void* d_ws, size_t ws_size,
                              hipStream_t stream) {
    const float* feats = (const float*)d_in[1];
    const float* W     = (const float*)d_in[2];
    const float* gamma = (const float*)d_in[3];
    const float* beta  = (const float*)d_in[4];
    const int*   oidx  = (const int*)d_in[5];
    float* out = (float*)d_out;

    const int Npts = in_sizes[1] / 64;   // 100000
    const int Nout = out_size / 64;      // ~2.63M

    float*          stats = (float*)d_ws;                       // 128 floats
    unsigned short* wfrag = (unsigned short*)((char*)d_ws + 1024);  // 27*4096 bf16

    hipMemsetAsync(d_out, 0, (size_t)out_size * sizeof(float), stream);

    hipLaunchKernelGGL(prep_kernel, dim3(432), dim3(256), 0, stream, W, wfrag, stats);

    int cgrid = (Npts + 63) / 64;
    hipLaunchKernelGGL(conv_scatter, dim3(cgrid), dim3(256), 0, stream,
                       feats, wfrag, oidx, out, Npts);

    hipLaunchKernelGGL(bn_stats, dim3(2048), dim3(256), 0, stream, out, stats, Nout);
    hipLaunchKernelGGL(bn_apply, dim3(2048), dim3(256), 0, stream, out, stats, gamma, beta, Nout);
}

// Round 2
// 734.171 us; speedup vs baseline: 1.7503x; 1.7503x over previous
//
#include <hip/hip_runtime.h>
#include <hip/hip_bf16.h>

typedef __bf16 v8bf __attribute__((ext_vector_type(8)));
typedef float  f32x4 __attribute__((ext_vector_type(4)));

#define KVOL 27

__device__ __forceinline__ unsigned short f2bf(float f) {
    unsigned int u = __float_as_uint(f);
    u = u + 0x7FFFu + ((u >> 16) & 1u);   // round-to-nearest-even
    return (unsigned short)(u >> 16);
}

// ---------------------------------------------------------------------------
// Prep: W [27][64in][64out] fp32 -> bf16 B-fragments for mfma_f32_16x16x32_bf16.
// Fragment layout: for tap k, col-tile t (16 outc), K-step s (32 inc):
//   lane l, elem i  holds  W[k][ s*32 + (l>>4)*8 + i ][ t*16 + (l&15) ]
// Also zeroes the 128-float stats accumulator.
// ---------------------------------------------------------------------------
__global__ __launch_bounds__(256) void prep_kernel(const float* __restrict__ W,
                                                   unsigned short* __restrict__ wfrag,
                                                   float* __restrict__ stats) {
    if (blockIdx.x == 0 && threadIdx.x < 128) stats[threadIdx.x] = 0.0f;
    int d = blockIdx.x * 256 + threadIdx.x;
    if (d < KVOL * 64 * 64) {
        int i    = d & 7;
        int lane = (d >> 3) & 63;
        int s    = (d >> 9) & 1;
        int t    = (d >> 10) & 3;
        int k    = d >> 12;
        int kin  = s * 32 + (lane >> 4) * 8 + i;
        int c    = t * 16 + (lane & 15);
        wfrag[d] = f2bf(W[k * 4096 + kin * 64 + c]);
    }
}

// ---------------------------------------------------------------------------
// Count contributions per output row.
// ---------------------------------------------------------------------------
__global__ __launch_bounds__(256) void count_kernel(const int* __restrict__ oidx,
                                                    int* __restrict__ cnt, int M) {
    for (int e = blockIdx.x * 256 + threadIdx.x; e < M; e += gridDim.x * 256)
        atomicAdd(&cnt[oidx[e]], 1);
}

// ---------------------------------------------------------------------------
// Zero only multi-contributor rows (cnt >= 2). 4 threads per row.
// ---------------------------------------------------------------------------
__global__ __launch_bounds__(256) void zero_multi(float* __restrict__ out,
                                                  const int* __restrict__ cnt, int Nout) {
    const int sub = threadIdx.x & 3;
    const long step = (long)gridDim.x * 64;
    for (long r = (long)blockIdx.x * 64 + (threadIdx.x >> 2); r < Nout; r += step) {
        if (cnt[r] > 1) {
            f32x4 z = {0.f, 0.f, 0.f, 0.f};
            f32x4* p = reinterpret_cast<f32x4*>(out + r * 64) + sub;
            p[0] = z; p[4] = z; p[8] = z; p[12] = z;
        }
    }
}

// ---------------------------------------------------------------------------
// Conv: block = 64 points, 4 waves. Per tap k: C[16x64] = A[16x64]*W_k via
// 8 MFMAs. Rows with cnt==1: plain nontemporal store + in-register BN stats.
// Rows with cnt>=2: atomic scatter (zeroed beforehand).
// ---------------------------------------------------------------------------
__global__ __launch_bounds__(256) void conv_scatter_fast(const float* __restrict__ feats,
                                                         const unsigned short* __restrict__ wfrag,
                                                         const int* __restrict__ oidx,
                                                         const int* __restrict__ cnt,
                                                         float* __restrict__ out,
                                                         float* __restrict__ stats,
                                                         int Npts) {
    __shared__ unsigned short As[64 * 64];   // bf16 A tile [point][inc]
    __shared__ int Is[64 * KVOL];            // out_idx tile
    __shared__ float red[256 * 8];           // stats reduction

    const int tid  = threadIdx.x;
    const int base = blockIdx.x * 64;

    #pragma unroll
    for (int e = 0; e < 4; ++e) {
        int lin = e * 1024 + tid * 4;
        int row = lin >> 6, col = lin & 63;
        float4 v = make_float4(0.f, 0.f, 0.f, 0.f);
        if (base + row < Npts)
            v = *reinterpret_cast<const float4*>(feats + (size_t)(base + row) * 64 + col);
        As[lin + 0] = f2bf(v.x);
        As[lin + 1] = f2bf(v.y);
        As[lin + 2] = f2bf(v.z);
        As[lin + 3] = f2bf(v.w);
    }
    for (int lin = tid; lin < 64 * KVOL; lin += 256) {
        int g = base * KVOL + lin;
        Is[lin] = (g < Npts * KVOL) ? oidx[g] : 0;
    }
    __syncthreads();

    const int w  = tid >> 6;
    const int l  = tid & 63;
    const int cl = l & 15;     // A-row / C-col within tile
    const int hi = l >> 4;

    const v8bf a0 = *reinterpret_cast<const v8bf*>(&As[(16 * w + cl) * 64 + hi * 8]);
    const v8bf a1 = *reinterpret_cast<const v8bf*>(&As[(16 * w + cl) * 64 + 32 + hi * 8]);
    const v8bf* wf = reinterpret_cast<const v8bf*>(wfrag);

    float s[4] = {0.f, 0.f, 0.f, 0.f};
    float q[4] = {0.f, 0.f, 0.f, 0.f};

    for (int k = 0; k < KVOL; ++k) {
        f32x4 acc[4];
        #pragma unroll
        for (int t = 0; t < 4; ++t) acc[t] = (f32x4){0.f, 0.f, 0.f, 0.f};

        #pragma unroll
        for (int t = 0; t < 4; ++t) {
            v8bf b0 = wf[((k * 4 + t) * 2 + 0) * 64 + l];
            v8bf b1 = wf[((k * 4 + t) * 2 + 1) * 64 + l];
            acc[t] = __builtin_amdgcn_mfma_f32_16x16x32_bf16(a0, b0, acc[t], 0, 0, 0);
            acc[t] = __builtin_amdgcn_mfma_f32_16x16x32_bf16(a1, b1, acc[t], 0, 0, 0);
        }

        #pragma unroll
        for (int r = 0; r < 4; ++r) {
            int lrow = 16 * w + hi * 4 + r;       // C row within block tile
            if (base + lrow < Npts) {
                int o = Is[lrow * KVOL + k];
                int m = cnt[o];
                float* dst = out + (size_t)o * 64 + cl;
                if (m == 1) {
                    #pragma unroll
                    for (int t = 0; t < 4; ++t) {
                        float v = acc[t][r];
                        __builtin_nontemporal_store(v, dst + t * 16);
                        s[t] += v;
                        q[t] += v * v;
                    }
                } else {
                    #pragma unroll
                    for (int t = 0; t < 4; ++t)
                        unsafeAtomicAdd(dst + t * 16, acc[t][r]);
                }
            }
        }
    }

    // Block-reduce single-contributor stats. Channel of (t, cl) = t*16 + cl.
    #pragma unroll
    for (int t = 0; t < 4; ++t) { red[tid * 8 + t] = s[t]; red[tid * 8 + 4 + t] = q[t]; }
    __syncthreads();
    if (tid < 16) {
        float a8[8] = {0.f, 0.f, 0.f, 0.f, 0.f, 0.f, 0.f, 0.f};
        for (int g = 0; g < 16; ++g)
            #pragma unroll
            for (int j = 0; j < 8; ++j) a8[j] += red[(g * 16 + tid) * 8 + j];
        #pragma unroll
        for (int t = 0; t < 4; ++t) {
            unsafeAtomicAdd(&stats[t * 16 + tid],      a8[t]);
            unsafeAtomicAdd(&stats[64 + t * 16 + tid], a8[4 + t]);
        }
    }
}

// ---------------------------------------------------------------------------
// Stats over multi-contributor rows only.
// ---------------------------------------------------------------------------
__global__ __launch_bounds__(256) void multi_stats(const float* __restrict__ out,
                                                   const int* __restrict__ cnt,
                                                   float* __restrict__ stats, int Nout) {
    const int tid = threadIdx.x;
    const int cg  = tid & 15;
    const int rs  = tid >> 4;
    f32x4 s = {0.f, 0.f, 0.f, 0.f}, q = {0.f, 0.f, 0.f, 0.f};
    for (long r = (long)blockIdx.x * 16 + rs; r < Nout; r += (long)gridDim.x * 16) {
        if (cnt[r] > 1) {
            f32x4 v = *reinterpret_cast<const f32x4*>(out + (size_t)r * 64 + cg * 4);
            s += v;
            q += v * v;
        }
    }
    __shared__ f32x4 sd[256];
    __shared__ f32x4 qd[256];
    sd[tid] = s; qd[tid] = q;
    __syncthreads();
    #pragma unroll
    for (int st = 8; st >= 1; st >>= 1) {
        if (rs < st) { sd[tid] += sd[tid + 16 * st]; qd[tid] += qd[tid + 16 * st]; }
        __syncthreads();
    }
    if (rs == 0) {
        #pragma unroll
        for (int c = 0; c < 4; ++c) {
            unsafeAtomicAdd(&stats[cg * 4 + c],      sd[tid][c]);
            unsafeAtomicAdd(&stats[64 + cg * 4 + c], qd[tid][c]);
        }
    }
}

// ---------------------------------------------------------------------------
// Full stats pass (fallback path).
// ---------------------------------------------------------------------------
__global__ __launch_bounds__(256) void bn_stats(const float* __restrict__ out,
                                                float* __restrict__ stats,
                                                int Nout) {
    const int tid = threadIdx.x;
    const int cg  = tid & 15;
    const int rs  = tid >> 4;
    f32x4 s = {0.f, 0.f, 0.f, 0.f}, q = {0.f, 0.f, 0.f, 0.f};
    for (long r = (long)blockIdx.x * 16 + rs; r < Nout; r += (long)gridDim.x * 16) {
        f32x4 v = *reinterpret_cast<const f32x4*>(out + (size_t)r * 64 + cg * 4);
        s += v;
        q += v * v;
    }
    __shared__ f32x4 sd[256];
    __shared__ f32x4 qd[256];
    sd[tid] = s; qd[tid] = q;
    __syncthreads();
    #pragma unroll
    for (int st = 8; st >= 1; st >>= 1) {
        if (rs < st) { sd[tid] += sd[tid + 16 * st]; qd[tid] += qd[tid + 16 * st]; }
        __syncthreads();
    }
    if (rs == 0) {
        #pragma unroll
        for (int c = 0; c < 4; ++c) {
            unsafeAtomicAdd(&stats[cg * 4 + c],      sd[tid][c]);
            unsafeAtomicAdd(&stats[64 + cg * 4 + c], qd[tid][c]);
        }
    }
}

// ---------------------------------------------------------------------------
// Fallback conv (round-1): pure atomic scatter into zeroed out.
// ---------------------------------------------------------------------------
__global__ __launch_bounds__(256) void conv_scatter_fb(const float* __restrict__ feats,
                                                       const unsigned short* __restrict__ wfrag,
                                                       const int* __restrict__ oidx,
                                                       float* __restrict__ out,
                                                       int Npts) {
    __shared__ unsigned short As[64 * 64];
    __shared__ int Is[64 * KVOL];
    const int tid  = threadIdx.x;
    const int base = blockIdx.x * 64;
    #pragma unroll
    for (int e = 0; e < 4; ++e) {
        int lin = e * 1024 + tid * 4;
        int row = lin >> 6, col = lin & 63;
        float4 v = make_float4(0.f, 0.f, 0.f, 0.f);
        if (base + row < Npts)
            v = *reinterpret_cast<const float4*>(feats + (size_t)(base + row) * 64 + col);
        As[lin + 0] = f2bf(v.x); As[lin + 1] = f2bf(v.y);
        As[lin + 2] = f2bf(v.z); As[lin + 3] = f2bf(v.w);
    }
    for (int lin = tid; lin < 64 * KVOL; lin += 256) {
        int g = base * KVOL + lin;
        Is[lin] = (g < Npts * KVOL) ? oidx[g] : 0;
    }
    __syncthreads();
    const int w = tid >> 6, l = tid & 63, cl = l & 15, hi = l >> 4;
    const v8bf a0 = *reinterpret_cast<const v8bf*>(&As[(16 * w + cl) * 64 + hi * 8]);
    const v8bf a1 = *reinterpret_cast<const v8bf*>(&As[(16 * w + cl) * 64 + 32 + hi * 8]);
    const v8bf* wf = reinterpret_cast<const v8bf*>(wfrag);
    for (int k = 0; k < KVOL; ++k) {
        f32x4 acc[4];
        #pragma unroll
        for (int t = 0; t < 4; ++t) acc[t] = (f32x4){0.f, 0.f, 0.f, 0.f};
        #pragma unroll
        for (int t = 0; t < 4; ++t) {
            v8bf b0 = wf[((k * 4 + t) * 2 + 0) * 64 + l];
            v8bf b1 = wf[((k * 4 + t) * 2 + 1) * 64 + l];
            acc[t] = __builtin_amdgcn_mfma_f32_16x16x32_bf16(a0, b0, acc[t], 0, 0, 0);
            acc[t] = __builtin_amdgcn_mfma_f32_16x16x32_bf16(a1, b1, acc[t], 0, 0, 0);
        }
        #pragma unroll
        for (int r = 0; r < 4; ++r) {
            int lrow = 16 * w + hi * 4 + r;
            if (base + lrow < Npts) {
                int o = Is[lrow * KVOL + k];
                float* dst = out + (size_t)o * 64 + cl;
                #pragma unroll
                for (int t = 0; t < 4; ++t)
                    unsafeAtomicAdd(dst + t * 16, acc[t][r]);
            }
        }
    }
}

// ---------------------------------------------------------------------------
// y = gamma*(x-mean)*rsqrt(var+eps)+beta, LeakyReLU(0.01). In place.
// ---------------------------------------------------------------------------
__global__ __launch_bounds__(256) void bn_apply(float* __restrict__ out,
                                                const float* __restrict__ stats,
                                                const float* __restrict__ gamma,
                                                const float* __restrict__ beta,
                                                int Nout) {
    const int tid = threadIdx.x;
    const int cg  = tid & 15;
    const int rs  = tid >> 4;
    const float inv = 1.0f / (float)Nout;
    f32x4 scale, shift;
    #pragma unroll
    for (int c = 0; c < 4; ++c) {
        float m   = stats[cg * 4 + c] * inv;
        float var = stats[64 + cg * 4 + c] * inv - m * m;
        float sc  = gamma[cg * 4 + c] * rsqrtf(var + 1e-5f);
        scale[c]  = sc;
        shift[c]  = beta[cg * 4 + c] - sc * m;
    }
    for (long r = (long)blockIdx.x * 16 + rs; r < Nout; r += (long)gridDim.x * 16) {
        f32x4* p = reinterpret_cast<f32x4*>(out + (size_t)r * 64 + cg * 4);
        f32x4 v = *p;
        v = v * scale + shift;
        #pragma unroll
        for (int c = 0; c < 4; ++c) v[c] = v[c] > 0.f ? v[c] : 0.01f * v[c];
        *p = v;
    }
}

extern "C" void kernel_launch(void* const* d_in, const int* in_sizes, int n_in,
                              void* d_out, int out_size, void* d_ws, size_t ws_size,
                              hipStream_t stream) {
    const float* feats = (const float*)d_in[1];
    const float* W     = (const float*)d_in[2];
    const float* gamma = (const float*)d_in[3];
    const float* beta  = (const float*)d_in[4];
    const int*   oidx  = (const int*)d_in[5];
    float* out = (float*)d_out;

    const int Npts = in_sizes[1] / 64;   // 100000
    const int Nout = out_size / 64;      // ~2.51M
    const int M    = Npts * KVOL;

    float*          stats = (float*)d_ws;                           // 128 floats @ 0
    unsigned short* wfrag = (unsigned short*)((char*)d_ws + 4096);  // 221184 B
    int*            cnt   = (int*)((char*)d_ws + (4096 + 221184 + 4095 & ~4095) + 4096);
    // (simple fixed layout: cnt at 256 KiB)
    cnt = (int*)((char*)d_ws + (256 << 10));
    const size_t ws_need = (256 << 10) + (size_t)Nout * sizeof(int);

    int cgrid = (Npts + 63) / 64;

    if (ws_size >= ws_need) {
        // FAST path: no full memset, no full stats pass.
        hipMemsetAsync(cnt, 0, (size_t)Nout * sizeof(int), stream);
        hipLaunchKernelGGL(prep_kernel, dim3(432), dim3(256), 0, stream, W, wfrag, stats);
        hipLaunchKernelGGL(count_kernel, dim3(2048), dim3(256), 0, stream, oidx, cnt, M);
        hipLaunchKernelGGL(zero_multi, dim3(2048), dim3(256), 0, stream, out, cnt, Nout);
        hipLaunchKernelGGL(conv_scatter_fast, dim3(cgrid), dim3(256), 0, stream,
                           feats, wfrag, oidx, cnt, out, stats, Npts);
        hipLaunchKernelGGL(multi_stats, dim3(2048), dim3(256), 0, stream, out, cnt, stats, Nout);
        hipLaunchKernelGGL(bn_apply, dim3(2048), dim3(256), 0, stream, out, stats, gamma, beta, Nout);
    } else {
        // Fallback: round-1 structure.
        hipMemsetAsync(d_out, 0, (size_t)out_size * sizeof(float), stream);
        hipLaunchKernelGGL(prep_kernel, dim3(432), dim3(256), 0, stream, W, wfrag, stats);
        hipLaunchKernelGGL(conv_scatter_fb, dim3(cgrid), dim3(256), 0, stream,
                           feats, wfrag, oidx, out, Npts);
        hipLaunchKernelGGL(bn_stats, dim3(2048), dim3(256), 0, stream, out, stats, Nout);
        hipLaunchKernelGGL(bn_apply, dim3(2048), dim3(256), 0, stream, out, stats, gamma, beta, Nout);
    }
}

// Round 3
// 642.150 us; speedup vs baseline: 2.0012x; 1.1433x over previous
//
#include <hip/hip_runtime.h>
#include <hip/hip_bf16.h>

typedef __bf16 v8bf __attribute__((ext_vector_type(8)));
typedef float  f32x4 __attribute__((ext_vector_type(4)));

#define KVOL 27

__device__ __forceinline__ unsigned short f2bf(float f) {
    unsigned int u = __float_as_uint(f);
    u = u + 0x7FFFu + ((u >> 16) & 1u);   // round-to-nearest-even
    return (unsigned short)(u >> 16);
}

// ---------------------------------------------------------------------------
// Prep: W [27][64in][64out] fp32 -> bf16 B-fragments for mfma_f32_16x16x32_bf16.
// lane l, elem i holds W[k][ s*32 + (l>>4)*8 + i ][ t*16 + (l&15) ]
// at ushort index (((k*4+t)*2+s)*64 + l)*8 + i. Also zeroes stats[128].
// ---------------------------------------------------------------------------
__global__ __launch_bounds__(256) void prep_kernel(const float* __restrict__ W,
                                                   unsigned short* __restrict__ wfrag,
                                                   float* __restrict__ stats) {
    if (blockIdx.x == 0 && threadIdx.x < 128) stats[threadIdx.x] = 0.0f;
    int d = blockIdx.x * 256 + threadIdx.x;
    if (d < KVOL * 64 * 64) {
        int i    = d & 7;
        int lane = (d >> 3) & 63;
        int s    = (d >> 9) & 1;
        int t    = (d >> 10) & 3;
        int k    = d >> 12;
        int kin  = s * 32 + (lane >> 4) * 8 + i;
        int c    = t * 16 + (lane & 15);
        wfrag[d] = f2bf(W[k * 4096 + kin * 64 + c]);
    }
}

__global__ __launch_bounds__(256) void count_kernel(const int* __restrict__ oidx,
                                                    int* __restrict__ cnt, int M) {
    for (int e = blockIdx.x * 256 + threadIdx.x; e < M; e += gridDim.x * 256)
        atomicAdd(&cnt[oidx[e]], 1);
}

// Zero only multi-contributor rows (cnt >= 2). 4 threads per row.
__global__ __launch_bounds__(256) void zero_multi(float* __restrict__ out,
                                                  const int* __restrict__ cnt, int Nout) {
    const int sub = threadIdx.x & 3;
    const long step = (long)gridDim.x * 64;
    for (long r = (long)blockIdx.x * 64 + (threadIdx.x >> 2); r < Nout; r += step) {
        if (cnt[r] > 1) {
            f32x4 z = {0.f, 0.f, 0.f, 0.f};
            f32x4* p = reinterpret_cast<f32x4*>(out + r * 64) + sub;
            p[0] = z; p[4] = z; p[8] = z; p[12] = z;
        }
    }
}

// ---------------------------------------------------------------------------
// Shared staging: A tile (bf16) + packed idx (sign bit = multi).
// ---------------------------------------------------------------------------
__device__ __forceinline__ void stage_tile(const float* __restrict__ feats,
                                           const int* __restrict__ oidx,
                                           const int* __restrict__ cnt,
                                           unsigned short* As, int* Is,
                                           int base, int Npts) {
    const int tid = threadIdx.x;
    #pragma unroll
    for (int e = 0; e < 4; ++e) {
        int lin = e * 1024 + tid * 4;
        int row = lin >> 6, col = lin & 63;
        float4 v = make_float4(0.f, 0.f, 0.f, 0.f);
        if (base + row < Npts)
            v = *reinterpret_cast<const float4*>(feats + (size_t)(base + row) * 64 + col);
        As[lin + 0] = f2bf(v.x);
        As[lin + 1] = f2bf(v.y);
        As[lin + 2] = f2bf(v.z);
        As[lin + 3] = f2bf(v.w);
    }
    for (int lin = tid; lin < 64 * KVOL; lin += 256) {
        int g = base * KVOL + lin;
        int iv = 0;
        if (g < Npts * KVOL) {
            int o = oidx[g];
            iv = o | (cnt[o] > 1 ? 0x80000000 : 0);
        }
        Is[lin] = iv;
    }
}

// ---------------------------------------------------------------------------
// Pass 1: conv -> stats (+ atomic scatter for multi rows only).
//   s accumulates ALL contributions (mean is linear: sum of row-sums ==
//   sum of contribution values). q accumulates single rows only; multi q
//   is added later by multi_stats from the accumulated rows.
// ---------------------------------------------------------------------------
__global__ __launch_bounds__(256) void conv_stats(const float* __restrict__ feats,
                                                  const unsigned short* __restrict__ wfrag,
                                                  const int* __restrict__ oidx,
                                                  const int* __restrict__ cnt,
                                                  float* __restrict__ out,
                                                  float* __restrict__ stats,
                                                  int Npts) {
    __shared__ unsigned short As[64 * 64];
    __shared__ int Is[64 * KVOL];
    __shared__ float red[256 * 8];

    const int tid  = threadIdx.x;
    const int base = blockIdx.x * 64;
    stage_tile(feats, oidx, cnt, As, Is, base, Npts);
    __syncthreads();

    const int w = tid >> 6, l = tid & 63, cl = l & 15, hi = l >> 4;
    const v8bf a0 = *reinterpret_cast<const v8bf*>(&As[(16 * w + cl) * 64 + hi * 8]);
    const v8bf a1 = *reinterpret_cast<const v8bf*>(&As[(16 * w + cl) * 64 + 32 + hi * 8]);
    const v8bf* wf = reinterpret_cast<const v8bf*>(wfrag);

    float s[4] = {0.f, 0.f, 0.f, 0.f};
    float q[4] = {0.f, 0.f, 0.f, 0.f};

    for (int k = 0; k < KVOL; ++k) {
        f32x4 acc[4];
        #pragma unroll
        for (int t = 0; t < 4; ++t) acc[t] = (f32x4){0.f, 0.f, 0.f, 0.f};
        #pragma unroll
        for (int t = 0; t < 4; ++t) {
            v8bf b0 = wf[((k * 4 + t) * 2 + 0) * 64 + l];
            v8bf b1 = wf[((k * 4 + t) * 2 + 1) * 64 + l];
            acc[t] = __builtin_amdgcn_mfma_f32_16x16x32_bf16(a0, b0, acc[t], 0, 0, 0);
            acc[t] = __builtin_amdgcn_mfma_f32_16x16x32_bf16(a1, b1, acc[t], 0, 0, 0);
        }
        #pragma unroll
        for (int r = 0; r < 4; ++r) {
            int lrow = 16 * w + hi * 4 + r;
            if (base + lrow < Npts) {
                int iv = Is[lrow * KVOL + k];
                if (iv >= 0) {                       // single-contributor row
                    #pragma unroll
                    for (int t = 0; t < 4; ++t) {
                        float v = acc[t][r];
                        s[t] += v;
                        q[t] += v * v;
                    }
                } else {                             // multi row: accumulate
                    int o = iv & 0x7fffffff;
                    float* dst = out + (size_t)o * 64 + cl;
                    #pragma unroll
                    for (int t = 0; t < 4; ++t) {
                        float v = acc[t][r];
                        s[t] += v;
                        unsafeAtomicAdd(dst + t * 16, v);
                    }
                }
            }
        }
    }

    #pragma unroll
    for (int t = 0; t < 4; ++t) { red[tid * 8 + t] = s[t]; red[tid * 8 + 4 + t] = q[t]; }
    __syncthreads();
    if (tid < 16) {
        float a8[8] = {0.f, 0.f, 0.f, 0.f, 0.f, 0.f, 0.f, 0.f};
        for (int g = 0; g < 16; ++g)
            #pragma unroll
            for (int j = 0; j < 8; ++j) a8[j] += red[(g * 16 + tid) * 8 + j];
        #pragma unroll
        for (int t = 0; t < 4; ++t) {
            unsafeAtomicAdd(&stats[t * 16 + tid],      a8[t]);
            unsafeAtomicAdd(&stats[64 + t * 16 + tid], a8[4 + t]);
        }
    }
}

// Sumsq of accumulated multi rows (sum already counted in pass 1).
__global__ __launch_bounds__(256) void multi_stats(const float* __restrict__ out,
                                                   const int* __restrict__ cnt,
                                                   float* __restrict__ stats, int Nout) {
    const int tid = threadIdx.x;
    const int cg  = tid & 15;
    const int rs  = tid >> 4;
    f32x4 q = {0.f, 0.f, 0.f, 0.f};
    for (long r = (long)blockIdx.x * 16 + rs; r < Nout; r += (long)gridDim.x * 16) {
        if (cnt[r] > 1) {
            f32x4 v = *reinterpret_cast<const f32x4*>(out + (size_t)r * 64 + cg * 4);
            q += v * v;
        }
    }
    __shared__ f32x4 qd[256];
    qd[tid] = q;
    __syncthreads();
    #pragma unroll
    for (int st = 8; st >= 1; st >>= 1) {
        if (rs < st) qd[tid] += qd[tid + 16 * st];
        __syncthreads();
    }
    if (rs == 0) {
        #pragma unroll
        for (int c = 0; c < 4; ++c)
            unsafeAtomicAdd(&stats[64 + cg * 4 + c], qd[tid][c]);
    }
}

// ---------------------------------------------------------------------------
// Pass 2: recompute conv, apply BN+LeakyReLU in-register, store final fp32
// for single rows. Multi rows handled by multi_apply.
// ---------------------------------------------------------------------------
__global__ __launch_bounds__(256) void conv_apply(const float* __restrict__ feats,
                                                  const unsigned short* __restrict__ wfrag,
                                                  const int* __restrict__ oidx,
                                                  const int* __restrict__ cnt,
                                                  const float* __restrict__ stats,
                                                  const float* __restrict__ gamma,
                                                  const float* __restrict__ beta,
                                                  float* __restrict__ out,
                                                  int Npts, int Nout) {
    __shared__ unsigned short As[64 * 64];
    __shared__ int Is[64 * KVOL];

    const int tid  = threadIdx.x;
    const int base = blockIdx.x * 64;
    stage_tile(feats, oidx, cnt, As, Is, base, Npts);
    __syncthreads();

    const int w = tid >> 6, l = tid & 63, cl = l & 15, hi = l >> 4;
    const v8bf a0 = *reinterpret_cast<const v8bf*>(&As[(16 * w + cl) * 64 + hi * 8]);
    const v8bf a1 = *reinterpret_cast<const v8bf*>(&As[(16 * w + cl) * 64 + 32 + hi * 8]);
    const v8bf* wf = reinterpret_cast<const v8bf*>(wfrag);

    const float inv = 1.0f / (float)Nout;
    float scale[4], shift[4];
    #pragma unroll
    for (int t = 0; t < 4; ++t) {
        int c = t * 16 + cl;
        float m   = stats[c] * inv;
        float var = stats[64 + c] * inv - m * m;
        float sc  = gamma[c] * rsqrtf(var + 1e-5f);
        scale[t]  = sc;
        shift[t]  = beta[c] - sc * m;
    }

    for (int k = 0; k < KVOL; ++k) {
        f32x4 acc[4];
        #pragma unroll
        for (int t = 0; t < 4; ++t) acc[t] = (f32x4){0.f, 0.f, 0.f, 0.f};
        #pragma unroll
        for (int t = 0; t < 4; ++t) {
            v8bf b0 = wf[((k * 4 + t) * 2 + 0) * 64 + l];
            v8bf b1 = wf[((k * 4 + t) * 2 + 1) * 64 + l];
            acc[t] = __builtin_amdgcn_mfma_f32_16x16x32_bf16(a0, b0, acc[t], 0, 0, 0);
            acc[t] = __builtin_amdgcn_mfma_f32_16x16x32_bf16(a1, b1, acc[t], 0, 0, 0);
        }
        #pragma unroll
        for (int r = 0; r < 4; ++r) {
            int lrow = 16 * w + hi * 4 + r;
            if (base + lrow < Npts) {
                int iv = Is[lrow * KVOL + k];
                if (iv >= 0) {                       // single row: finalize
                    float* dst = out + (size_t)iv * 64 + cl;
                    #pragma unroll
                    for (int t = 0; t < 4; ++t) {
                        float y = acc[t][r] * scale[t] + shift[t];
                        y = y > 0.f ? y : 0.01f * y;
                        __builtin_nontemporal_store(y, dst + t * 16);
                    }
                }
            }
        }
    }
}

// BN+LeakyReLU in place for multi rows.
__global__ __launch_bounds__(256) void multi_apply(float* __restrict__ out,
                                                   const int* __restrict__ cnt,
                                                   const float* __restrict__ stats,
                                                   const float* __restrict__ gamma,
                                                   const float* __restrict__ beta,
                                                   int Nout) {
    const int tid = threadIdx.x;
    const int cg  = tid & 15;
    const int rs  = tid >> 4;
    const float inv = 1.0f / (float)Nout;
    f32x4 scale, shift;
    #pragma unroll
    for (int c = 0; c < 4; ++c) {
        float m   = stats[cg * 4 + c] * inv;
        float var = stats[64 + cg * 4 + c] * inv - m * m;
        float sc  = gamma[cg * 4 + c] * rsqrtf(var + 1e-5f);
        scale[c]  = sc;
        shift[c]  = beta[cg * 4 + c] - sc * m;
    }
    for (long r = (long)blockIdx.x * 16 + rs; r < Nout; r += (long)gridDim.x * 16) {
        if (cnt[r] > 1) {
            f32x4* p = reinterpret_cast<f32x4*>(out + (size_t)r * 64 + cg * 4);
            f32x4 v = *p;
            v = v * scale + shift;
            #pragma unroll
            for (int c = 0; c < 4; ++c) v[c] = v[c] > 0.f ? v[c] : 0.01f * v[c];
            *p = v;
        }
    }
}

// ---------------------------------------------------------------------------
// Fallback path (round-1 structure).
// ---------------------------------------------------------------------------
__global__ __launch_bounds__(256) void conv_scatter_fb(const float* __restrict__ feats,
                                                       const unsigned short* __restrict__ wfrag,
                                                       const int* __restrict__ oidx,
                                                       float* __restrict__ out,
                                                       int Npts) {
    __shared__ unsigned short As[64 * 64];
    __shared__ int Is[64 * KVOL];
    const int tid  = threadIdx.x;
    const int base = blockIdx.x * 64;
    #pragma unroll
    for (int e = 0; e < 4; ++e) {
        int lin = e * 1024 + tid * 4;
        int row = lin >> 6, col = lin & 63;
        float4 v = make_float4(0.f, 0.f, 0.f, 0.f);
        if (base + row < Npts)
            v = *reinterpret_cast<const float4*>(feats + (size_t)(base + row) * 64 + col);
        As[lin + 0] = f2bf(v.x); As[lin + 1] = f2bf(v.y);
        As[lin + 2] = f2bf(v.z); As[lin + 3] = f2bf(v.w);
    }
    for (int lin = tid; lin < 64 * KVOL; lin += 256) {
        int g = base * KVOL + lin;
        Is[lin] = (g < Npts * KVOL) ? oidx[g] : 0;
    }
    __syncthreads();
    const int w = tid >> 6, l = tid & 63, cl = l & 15, hi = l >> 4;
    const v8bf a0 = *reinterpret_cast<const v8bf*>(&As[(16 * w + cl) * 64 + hi * 8]);
    const v8bf a1 = *reinterpret_cast<const v8bf*>(&As[(16 * w + cl) * 64 + 32 + hi * 8]);
    const v8bf* wf = reinterpret_cast<const v8bf*>(wfrag);
    for (int k = 0; k < KVOL; ++k) {
        f32x4 acc[4];
        #pragma unroll
        for (int t = 0; t < 4; ++t) acc[t] = (f32x4){0.f, 0.f, 0.f, 0.f};
        #pragma unroll
        for (int t = 0; t < 4; ++t) {
            v8bf b0 = wf[((k * 4 + t) * 2 + 0) * 64 + l];
            v8bf b1 = wf[((k * 4 + t) * 2 + 1) * 64 + l];
            acc[t] = __builtin_amdgcn_mfma_f32_16x16x32_bf16(a0, b0, acc[t], 0, 0, 0);
            acc[t] = __builtin_amdgcn_mfma_f32_16x16x32_bf16(a1, b1, acc[t], 0, 0, 0);
        }
        #pragma unroll
        for (int r = 0; r < 4; ++r) {
            int lrow = 16 * w + hi * 4 + r;
            if (base + lrow < Npts) {
                int o = Is[lrow * KVOL + k];
                float* dst = out + (size_t)o * 64 + cl;
                #pragma unroll
                for (int t = 0; t < 4; ++t)
                    unsafeAtomicAdd(dst + t * 16, acc[t][r]);
            }
        }
    }
}

__global__ __launch_bounds__(256) void bn_stats(const float* __restrict__ out,
                                                float* __restrict__ stats,
                                                int Nout) {
    const int tid = threadIdx.x;
    const int cg  = tid & 15;
    const int rs  = tid >> 4;
    f32x4 s = {0.f, 0.f, 0.f, 0.f}, q = {0.f, 0.f, 0.f, 0.f};
    for (long r = (long)blockIdx.x * 16 + rs; r < Nout; r += (long)gridDim.x * 16) {
        f32x4 v = *reinterpret_cast<const f32x4*>(out + (size_t)r * 64 + cg * 4);
        s += v;
        q += v * v;
    }
    __shared__ f32x4 sd[256];
    __shared__ f32x4 qd[256];
    sd[tid] = s; qd[tid] = q;
    __syncthreads();
    #pragma unroll
    for (int st = 8; st >= 1; st >>= 1) {
        if (rs < st) { sd[tid] += sd[tid + 16 * st]; qd[tid] += qd[tid + 16 * st]; }
        __syncthreads();
    }
    if (rs == 0) {
        #pragma unroll
        for (int c = 0; c < 4; ++c) {
            unsafeAtomicAdd(&stats[cg * 4 + c],      sd[tid][c]);
            unsafeAtomicAdd(&stats[64 + cg * 4 + c], qd[tid][c]);
        }
    }
}

__global__ __launch_bounds__(256) void bn_apply(float* __restrict__ out,
                                                const float* __restrict__ stats,
                                                const float* __restrict__ gamma,
                                                const float* __restrict__ beta,
                                                int Nout) {
    const int tid = threadIdx.x;
    const int cg  = tid & 15;
    const int rs  = tid >> 4;
    const float inv = 1.0f / (float)Nout;
    f32x4 scale, shift;
    #pragma unroll
    for (int c = 0; c < 4; ++c) {
        float m   = stats[cg * 4 + c] * inv;
        float var = stats[64 + cg * 4 + c] * inv - m * m;
        float sc  = gamma[cg * 4 + c] * rsqrtf(var + 1e-5f);
        scale[c]  = sc;
        shift[c]  = beta[cg * 4 + c] - sc * m;
    }
    for (long r = (long)blockIdx.x * 16 + rs; r < Nout; r += (long)gridDim.x * 16) {
        f32x4* p = reinterpret_cast<f32x4*>(out + (size_t)r * 64 + cg * 4);
        f32x4 v = *p;
        v = v * scale + shift;
        #pragma unroll
        for (int c = 0; c < 4; ++c) v[c] = v[c] > 0.f ? v[c] : 0.01f * v[c];
        *p = v;
    }
}

extern "C" void kernel_launch(void* const* d_in, const int* in_sizes, int n_in,
                              void* d_out, int out_size, void* d_ws, size_t ws_size,
                              hipStream_t stream) {
    const float* feats = (const float*)d_in[1];
    const float* W     = (const float*)d_in[2];
    const float* gamma = (const float*)d_in[3];
    const float* beta  = (const float*)d_in[4];
    const int*   oidx  = (const int*)d_in[5];
    float* out = (float*)d_out;

    const int Npts = in_sizes[1] / 64;   // 100000
    const int Nout = out_size / 64;      // ~2.51M
    const int M    = Npts * KVOL;

    float*          stats = (float*)d_ws;                           // 128 floats @ 0
    unsigned short* wfrag = (unsigned short*)((char*)d_ws + 4096);  // 221184 B
    int*            cnt   = (int*)((char*)d_ws + (256 << 10));      // Nout ints
    const size_t ws_need = (256 << 10) + (size_t)Nout * sizeof(int);

    int cgrid = (Npts + 63) / 64;

    if (ws_size >= ws_need) {
        hipMemsetAsync(cnt, 0, (size_t)Nout * sizeof(int), stream);
        hipLaunchKernelGGL(prep_kernel, dim3(432), dim3(256), 0, stream, W, wfrag, stats);
        hipLaunchKernelGGL(count_kernel, dim3(2048), dim3(256), 0, stream, oidx, cnt, M);
        hipLaunchKernelGGL(zero_multi, dim3(2048), dim3(256), 0, stream, out, cnt, Nout);
        hipLaunchKernelGGL(conv_stats, dim3(cgrid), dim3(256), 0, stream,
                           feats, wfrag, oidx, cnt, out, stats, Npts);
        hipLaunchKernelGGL(multi_stats, dim3(2048), dim3(256), 0, stream, out, cnt, stats, Nout);
        hipLaunchKernelGGL(conv_apply, dim3(cgrid), dim3(256), 0, stream,
                           feats, wfrag, oidx, cnt, stats, gamma, beta, out, Npts, Nout);
        hipLaunchKernelGGL(multi_apply, dim3(2048), dim3(256), 0, stream,
                           out, cnt, stats, gamma, beta, Nout);
    } else {
        hipMemsetAsync(d_out, 0, (size_t)out_size * sizeof(float), stream);
        hipLaunchKernelGGL(prep_kernel, dim3(432), dim3(256), 0, stream, W, wfrag, stats);
        hipLaunchKernelGGL(conv_scatter_fb, dim3(cgrid), dim3(256), 0, stream,
                           feats, wfrag, oidx, out, Npts);
        hipLaunchKernelGGL(bn_stats, dim3(2048), dim3(256), 0, stream, out, stats, Nout);
        hipLaunchKernelGGL(bn_apply, dim3(2048), dim3(256), 0, stream, out, stats, gamma, beta, Nout);
    }
}